// Round 1
// baseline (3147.658 us; speedup 1.0000x reference)
//
#include <hip/hip_runtime.h>
#include <math.h>

// Problem constants (MultiQueryAttention_71734543778305)
#define B_    2
#define S_    2048
#define HID_  2048
#define NH_   16
#define HD_   128
#define MTOT  4096          // B*S
#define QKV_LD 2304         // Q(2048) | K(128) | V(128) concatenated per row

// ---------------------------------------------------------------------------
// fp32 GEMM, 128x128 block tile, BK=16, 256 threads, 8x8 outputs/thread.
// Row/col ownership split into two 64-halves so LDS reads are b128 and
// conflict-free-ish (row pad +4 floats).
// ---------------------------------------------------------------------------
#define FMA4(accv, as, bv)                  \
    accv.x = fmaf(as, bv.x, accv.x);        \
    accv.y = fmaf(as, bv.y, accv.y);        \
    accv.z = fmaf(as, bv.z, accv.z);        \
    accv.w = fmaf(as, bv.w, accv.w)

__global__ __launch_bounds__(256, 2) void gemm_out_kernel(
    const float* __restrict__ A, const float* __restrict__ W,
    const float* __restrict__ bias, float* __restrict__ C,
    int M, int N, int K)
{
    __shared__ float As[16][132];
    __shared__ float Bs[16][132];
    const int t  = threadIdx.x;
    const int tx = t & 15, ty = t >> 4;
    const long bm = (long)blockIdx.y * 128;
    const long bn = (long)blockIdx.x * 128;

    float4 acc[2][4][2];
#pragma unroll
    for (int ih = 0; ih < 2; ih++)
#pragma unroll
        for (int ii = 0; ii < 4; ii++)
#pragma unroll
            for (int jh = 0; jh < 2; jh++)
                acc[ih][ii][jh] = make_float4(0.f, 0.f, 0.f, 0.f);

    const int a_kk = t & 15;   // k within tile
    const int a_r0 = t >> 4;   // row group
    const int b_n  = t & 127;
    const int b_k0 = t >> 7;

    for (int k0 = 0; k0 < K; k0 += 16) {
#pragma unroll
        for (int i = 0; i < 8; i++)
            As[a_kk][a_r0 + 16 * i] =
                A[(bm + a_r0 + 16 * i) * (long)K + (k0 + a_kk)];
#pragma unroll
        for (int i = 0; i < 8; i++)
            Bs[b_k0 + 2 * i][b_n] =
                W[(long)(k0 + b_k0 + 2 * i) * N + (bn + b_n)];
        __syncthreads();
#pragma unroll
        for (int kk = 0; kk < 16; kk++) {
            float4 a0 = *(const float4*)&As[kk][4 * ty];
            float4 a1 = *(const float4*)&As[kk][64 + 4 * ty];
            float4 b0 = *(const float4*)&Bs[kk][4 * tx];
            float4 b1 = *(const float4*)&Bs[kk][64 + 4 * tx];
            FMA4(acc[0][0][0], a0.x, b0); FMA4(acc[0][0][1], a0.x, b1);
            FMA4(acc[0][1][0], a0.y, b0); FMA4(acc[0][1][1], a0.y, b1);
            FMA4(acc[0][2][0], a0.z, b0); FMA4(acc[0][2][1], a0.z, b1);
            FMA4(acc[0][3][0], a0.w, b0); FMA4(acc[0][3][1], a0.w, b1);
            FMA4(acc[1][0][0], a1.x, b0); FMA4(acc[1][0][1], a1.x, b1);
            FMA4(acc[1][1][0], a1.y, b0); FMA4(acc[1][1][1], a1.y, b1);
            FMA4(acc[1][2][0], a1.z, b0); FMA4(acc[1][2][1], a1.z, b1);
            FMA4(acc[1][3][0], a1.w, b0); FMA4(acc[1][3][1], a1.w, b1);
        }
        __syncthreads();
    }
#pragma unroll
    for (int ih = 0; ih < 2; ih++) {
#pragma unroll
        for (int ii = 0; ii < 4; ii++) {
            long row = bm + 64 * ih + 4 * ty + ii;
#pragma unroll
            for (int jh = 0; jh < 2; jh++) {
                long col = bn + 64 * jh + 4 * tx;
                float4 bv = *(const float4*)&bias[col];
                float4 o = acc[ih][ii][jh];
                o.x += bv.x; o.y += bv.y; o.z += bv.z; o.w += bv.w;
                *(float4*)&C[row * (long)N + col] = o;
            }
        }
    }
}

// Fused Q|K|V projection. blockIdx.x in [0,18): tiles 0..15 -> Wq,
// 16 -> Wk, 17 -> Wv. Output row-stride QKV_LD = 2304.
__global__ __launch_bounds__(256, 2) void gemm_qkv_kernel(
    const float* __restrict__ A,
    const float* __restrict__ Wq, const float* __restrict__ bq,
    const float* __restrict__ Wk, const float* __restrict__ bk,
    const float* __restrict__ Wv, const float* __restrict__ bv,
    float* __restrict__ C)
{
    const int K = HID_;
    const long bn_out = (long)blockIdx.x * 128;
    const float* W; const float* bias; long bn; int N;
    if (bn_out < 2048)      { W = Wq; bias = bq; bn = bn_out;        N = 2048; }
    else if (bn_out < 2176) { W = Wk; bias = bk; bn = bn_out - 2048; N = 128;  }
    else                    { W = Wv; bias = bv; bn = bn_out - 2176; N = 128;  }

    __shared__ float As[16][132];
    __shared__ float Bs[16][132];
    const int t  = threadIdx.x;
    const int tx = t & 15, ty = t >> 4;
    const long bm = (long)blockIdx.y * 128;

    float4 acc[2][4][2];
#pragma unroll
    for (int ih = 0; ih < 2; ih++)
#pragma unroll
        for (int ii = 0; ii < 4; ii++)
#pragma unroll
            for (int jh = 0; jh < 2; jh++)
                acc[ih][ii][jh] = make_float4(0.f, 0.f, 0.f, 0.f);

    const int a_kk = t & 15;
    const int a_r0 = t >> 4;
    const int b_n  = t & 127;
    const int b_k0 = t >> 7;

    for (int k0 = 0; k0 < K; k0 += 16) {
#pragma unroll
        for (int i = 0; i < 8; i++)
            As[a_kk][a_r0 + 16 * i] =
                A[(bm + a_r0 + 16 * i) * (long)K + (k0 + a_kk)];
#pragma unroll
        for (int i = 0; i < 8; i++)
            Bs[b_k0 + 2 * i][b_n] =
                W[(long)(k0 + b_k0 + 2 * i) * N + (bn + b_n)];
        __syncthreads();
#pragma unroll
        for (int kk = 0; kk < 16; kk++) {
            float4 a0 = *(const float4*)&As[kk][4 * ty];
            float4 a1 = *(const float4*)&As[kk][64 + 4 * ty];
            float4 b0 = *(const float4*)&Bs[kk][4 * tx];
            float4 b1 = *(const float4*)&Bs[kk][64 + 4 * tx];
            FMA4(acc[0][0][0], a0.x, b0); FMA4(acc[0][0][1], a0.x, b1);
            FMA4(acc[0][1][0], a0.y, b0); FMA4(acc[0][1][1], a0.y, b1);
            FMA4(acc[0][2][0], a0.z, b0); FMA4(acc[0][2][1], a0.z, b1);
            FMA4(acc[0][3][0], a0.w, b0); FMA4(acc[0][3][1], a0.w, b1);
            FMA4(acc[1][0][0], a1.x, b0); FMA4(acc[1][0][1], a1.x, b1);
            FMA4(acc[1][1][0], a1.y, b0); FMA4(acc[1][1][1], a1.y, b1);
            FMA4(acc[1][2][0], a1.z, b0); FMA4(acc[1][2][1], a1.z, b1);
            FMA4(acc[1][3][0], a1.w, b0); FMA4(acc[1][3][1], a1.w, b1);
        }
        __syncthreads();
    }
#pragma unroll
    for (int ih = 0; ih < 2; ih++) {
#pragma unroll
        for (int ii = 0; ii < 4; ii++) {
            long row = bm + 64 * ih + 4 * ty + ii;
#pragma unroll
            for (int jh = 0; jh < 2; jh++) {
                long colw = bn + 64 * jh + 4 * tx;           // col within W
                float4 bv = *(const float4*)&bias[colw];
                float4 o = acc[ih][ii][jh];
                o.x += bv.x; o.y += bv.y; o.z += bv.z; o.w += bv.w;
                *(float4*)&C[row * (long)QKV_LD + bn_out + 64 * jh + 4 * tx] = o;
            }
        }
    }
}

// ---------------------------------------------------------------------------
// Flash-style MQA attention. One block = (b, h, 32-query tile).
// Online softmax with m/l/alpha in LDS. Causal mask hardcoded (triu k=1);
// pad mask read from input and applied as -1e9*pad (matches reference).
// LDS rows padded +4 floats -> conflict-free b128 reads in both phases.
// ---------------------------------------------------------------------------
__global__ __launch_bounds__(256, 2) void attn_kernel(
    const float* __restrict__ qkv, const float* __restrict__ pad,
    float* __restrict__ outp)
{
    const int qt = blockIdx.x;   // 0..63, query tile of 32
    const int h  = blockIdx.y;   // 0..15
    const int b  = blockIdx.z;   // 0..1
    const int t  = threadIdx.x;

    __shared__ float Qs[32][132];
    __shared__ float Ks[32][132];
    __shared__ float Vs[32][132];
    __shared__ float Ss[32][33];
    __shared__ float mrow[32], lrow[32], arow[32], padm[32];

    const long rowbase = (long)b * S_;

    // load Q tile [32 x 128]
#pragma unroll
    for (int i = 0; i < 4; i++) {
        int idx = t + 256 * i;           // 0..1023 float4 slots
        int r   = idx >> 5;
        int d4  = idx & 31;
        const float* src = qkv + (rowbase + (long)qt * 32 + r) * QKV_LD
                               + h * HD_ + d4 * 4;
        *(float4*)&Qs[r][d4 * 4] = *(const float4*)src;
    }
    if (t < 32) { mrow[t] = -1e30f; lrow[t] = 0.f; }

    const int ro = t >> 3;       // output row owned (0..31)
    const int a7 = t & 7;

    float4 acc[4];
#pragma unroll
    for (int m = 0; m < 4; m++) acc[m] = make_float4(0.f, 0.f, 0.f, 0.f);

    const float scale = 0.08838834764831845f;   // 1/sqrt(128)

    for (int kt = 0; kt <= qt; kt++) {
#pragma unroll
        for (int i = 0; i < 4; i++) {
            int idx = t + 256 * i;
            int r   = idx >> 5;
            int d4  = idx & 31;
            const float* src = qkv + (rowbase + (long)kt * 32 + r) * QKV_LD;
            *(float4*)&Ks[r][d4 * 4] = *(const float4*)(src + 2048 + d4 * 4);
            *(float4*)&Vs[r][d4 * 4] = *(const float4*)(src + 2176 + d4 * 4);
        }
        if (t < 32) padm[t] = pad[rowbase + kt * 32 + t];
        __syncthreads();

        // ---- scores: row ro, cols {a7, a7+8, a7+16, a7+24} ----
        {
            float s[4] = {0.f, 0.f, 0.f, 0.f};
            const float4* q4 = (const float4*)&Qs[ro][0];
            const float4* k0 = (const float4*)&Ks[a7][0];
            const float4* k1 = (const float4*)&Ks[a7 + 8][0];
            const float4* k2 = (const float4*)&Ks[a7 + 16][0];
            const float4* k3 = (const float4*)&Ks[a7 + 24][0];
#pragma unroll 8
            for (int d4 = 0; d4 < 32; d4++) {
                float4 q = q4[d4];
                float4 kv;
                kv = k0[d4]; s[0] += q.x*kv.x + q.y*kv.y + q.z*kv.z + q.w*kv.w;
                kv = k1[d4]; s[1] += q.x*kv.x + q.y*kv.y + q.z*kv.z + q.w*kv.w;
                kv = k2[d4]; s[2] += q.x*kv.x + q.y*kv.y + q.z*kv.z + q.w*kv.w;
                kv = k3[d4]; s[3] += q.x*kv.x + q.y*kv.y + q.z*kv.z + q.w*kv.w;
            }
            const int qg = qt * 32 + ro;
#pragma unroll
            for (int j = 0; j < 4; j++) {
                int c  = a7 + 8 * j;
                int kg = kt * 32 + c;
                float val = s[j] * scale;
                if (kg > qg) val -= 1e9f;          // causal (strict upper tri)
                val -= padm[c] * 1e9f;             // key padding
                Ss[ro][c] = val;
            }
        }
        __syncthreads();

        // ---- online softmax state update (one thread per row) ----
        if (t < 32) {
            const int r = t;
            float mold = mrow[r];
            float mx = mold;
#pragma unroll 8
            for (int c = 0; c < 32; c++) mx = fmaxf(mx, Ss[r][c]);
            float alpha = __expf(mold - mx);
            float sum = 0.f;
#pragma unroll 8
            for (int c = 0; c < 32; c++) {
                float p = __expf(Ss[r][c] - mx);
                Ss[r][c] = p;
                sum += p;
            }
            lrow[r] = lrow[r] * alpha + sum;
            mrow[r] = mx;
            arow[r] = alpha;
        }
        __syncthreads();

        // ---- O = O*alpha + P @ V (thread owns row ro, 4 scattered float4) ----
        {
            float alpha = arow[ro];
#pragma unroll
            for (int m = 0; m < 4; m++) {
                acc[m].x *= alpha; acc[m].y *= alpha;
                acc[m].z *= alpha; acc[m].w *= alpha;
            }
#pragma unroll 4
            for (int c = 0; c < 32; c++) {
                float p = Ss[ro][c];
                const float4* v4 = (const float4*)&Vs[c][0];
#pragma unroll
                for (int m = 0; m < 4; m++) {
                    float4 v = v4[a7 + 8 * m];
                    acc[m].x = fmaf(p, v.x, acc[m].x);
                    acc[m].y = fmaf(p, v.y, acc[m].y);
                    acc[m].z = fmaf(p, v.z, acc[m].z);
                    acc[m].w = fmaf(p, v.w, acc[m].w);
                }
            }
        }
        __syncthreads();
    }

    // ---- epilogue: normalize and store to [B*S, HID] (head-interleaved) ----
    float inv = 1.f / lrow[ro];
    float* dst = outp + (rowbase + (long)qt * 32 + ro) * HID_ + h * HD_;
#pragma unroll
    for (int m = 0; m < 4; m++) {
        float4 o = acc[m];
        o.x *= inv; o.y *= inv; o.z *= inv; o.w *= inv;
        *(float4*)&dst[(a7 + 8 * m) * 4] = o;
    }
}

// ---------------------------------------------------------------------------
extern "C" void kernel_launch(void* const* d_in, const int* in_sizes, int n_in,
                              void* d_out, int out_size, void* d_ws, size_t ws_size,
                              hipStream_t stream)
{
    const float* hidden = (const float*)d_in[0];
    // d_in[1] = causal mask: deterministic triu(k=1), hardcoded in attn_kernel
    const float* pad = (const float*)d_in[2];
    const float* Wq  = (const float*)d_in[3];
    const float* bq  = (const float*)d_in[4];
    const float* Wk  = (const float*)d_in[5];
    const float* bk  = (const float*)d_in[6];
    const float* Wv  = (const float*)d_in[7];
    const float* bv  = (const float*)d_in[8];
    const float* Wo  = (const float*)d_in[9];
    const float* bo  = (const float*)d_in[10];
    float* out = (float*)d_out;

    // workspace: qkv [4096][2304] fp32 (37.7 MB) | attn [4096][2048] fp32 (33.6 MB)
    char*  ws   = (char*)d_ws;
    float* qkv  = (float*)ws;
    float* attn = (float*)(ws + (size_t)MTOT * QKV_LD * sizeof(float));

    dim3 blk(256);
    gemm_qkv_kernel<<<dim3(18, 32), blk, 0, stream>>>(hidden, Wq, bq, Wk, bk,
                                                      Wv, bv, qkv);
    attn_kernel<<<dim3(64, NH_, B_), blk, 0, stream>>>(qkv, pad, attn);
    gemm_out_kernel<<<dim3(16, 32), blk, 0, stream>>>(attn, Wo, bo, out,
                                                      MTOT, HID_, HID_);
}

// Round 2
// 1811.915 us; speedup vs baseline: 1.7372x; 1.7372x over previous
//
#include <hip/hip_runtime.h>
#include <hip/hip_bf16.h>
#include <math.h>

// Problem constants (MultiQueryAttention_71734543778305)
#define B_    2
#define S_    2048
#define HID_  2048
#define NH_   16
#define HD_   128
#define MTOT  4096          // B*S
#define QKV_N 2304          // Q(2048) | K(128) | V(128)

typedef short bf16x8 __attribute__((ext_vector_type(8)));   // 8 bf16 in 4 VGPRs
typedef float f32x4  __attribute__((ext_vector_type(4)));

__device__ __forceinline__ ushort f2bf(float f) {
    __hip_bfloat16 h = __float2bfloat16(f);   // RTNE
    ushort u; __builtin_memcpy(&u, &h, 2); return u;
}

// async global->LDS, 16B per lane; LDS dest = wave-uniform base + lane*16
__device__ __forceinline__ void gload_lds16(const void* g, void* l) {
    __builtin_amdgcn_global_load_lds(
        (const __attribute__((address_space(1))) void*)g,
        (__attribute__((address_space(3))) void*)l, 16, 0, 0);
}

// ---------------------------------------------------------------------------
// fp32 -> bf16 elementwise cast (8 elems/thread, exact-cover grid)
// ---------------------------------------------------------------------------
__global__ void cast_f32_bf16(const float* __restrict__ in, ushort* __restrict__ out)
{
    long i = ((long)blockIdx.x * 256 + threadIdx.x) * 8;
    float4 a = *(const float4*)&in[i];
    float4 b = *(const float4*)&in[i + 4];
    uint4 o;
    o.x = (uint)f2bf(a.x) | ((uint)f2bf(a.y) << 16);
    o.y = (uint)f2bf(a.z) | ((uint)f2bf(a.w) << 16);
    o.z = (uint)f2bf(b.x) | ((uint)f2bf(b.y) << 16);
    o.w = (uint)f2bf(b.z) | ((uint)f2bf(b.w) << 16);
    *(uint4*)&out[i] = o;
}

// ---------------------------------------------------------------------------
// W [2048][N] fp32  ->  T rows [rowoff..rowoff+N) of [*][2048] bf16 (transposed)
// ---------------------------------------------------------------------------
__global__ void transcast(const float* __restrict__ W, ushort* __restrict__ T,
                          int N, int rowoff)
{
    __shared__ float tile[32][33];
    const int tx = threadIdx.x & 31, ty = threadIdx.x >> 5;
    const int n0 = blockIdx.x * 32, k0 = blockIdx.y * 32;
#pragma unroll
    for (int i = 0; i < 4; i++)
        tile[ty + 8 * i][tx] = W[(long)(k0 + ty + 8 * i) * N + n0 + tx];
    __syncthreads();
#pragma unroll
    for (int i = 0; i < 4; i++)
        T[(long)(rowoff + n0 + ty + 8 * i) * 2048 + k0 + tx] = f2bf(tile[tx][ty + 8 * i]);
}

__global__ void fuse_bias(const float* __restrict__ bq, const float* __restrict__ bk,
                          const float* __restrict__ bv, float* __restrict__ bqkv)
{
    int i = blockIdx.x * 256 + threadIdx.x;
    if (i < 2048)      bqkv[i] = bq[i];
    else if (i < 2176) bqkv[i] = bk[i - 2048];
    else if (i < QKV_N) bqkv[i] = bv[i - 2176];
}

// ---------------------------------------------------------------------------
// bf16 MFMA GEMM (m97 structure): C[m][n] = sum_k A[m][k] * Bt[n][k] + bias[n]
// 128x128 tile, BK=32, 256 thr / 4 waves, each wave 64x64 via 4x4 16x16x32 MFMA.
// A [M][K] bf16, Bt [N][K] bf16, bias fp32. BF16OUT: store bf16 else fp32.
// ---------------------------------------------------------------------------
template <bool BF16OUT>
__global__ __launch_bounds__(256, 2) void gemm_mfma(
    const ushort* __restrict__ A, const ushort* __restrict__ Bt,
    const float* __restrict__ bias, void* __restrict__ Cvoid,
    int K, int ldc)
{
    __shared__ __align__(16) ushort As[128 * 32];
    __shared__ __align__(16) ushort Bs[128 * 32];
    const int t = threadIdx.x;
    const int w = t >> 6, l = t & 63;
    const long bm = (long)blockIdx.y * 128;
    const long bn = (long)blockIdx.x * 128;

    f32x4 acc[4][4];
#pragma unroll
    for (int i = 0; i < 4; i++)
#pragma unroll
        for (int j = 0; j < 4; j++) acc[i][j] = (f32x4){0.f, 0.f, 0.f, 0.f};

    // staging: LDS row-major [128][32] bf16; round r covers rows r*64..r*64+63
    const int srow = w * 16 + (l >> 2);
    const int scol = (l & 3) * 8;
    const ushort* Ag0 = A + (bm + srow) * (long)K + scol;
    const ushort* Ag1 = A + (bm + srow + 64) * (long)K + scol;
    const ushort* Bg0 = Bt + (bn + srow) * (long)K + scol;
    const ushort* Bg1 = Bt + (bn + srow + 64) * (long)K + scol;
    ushort* Al0 = As + w * 512;          // wave-uniform LDS bases (1KB/wave)
    ushort* Al1 = As + 2048 + w * 512;
    ushort* Bl0 = Bs + w * 512;
    ushort* Bl1 = Bs + 2048 + w * 512;

    const int mrow = l & 15, kq = l >> 4;
    const int moff = (w & 1) * 64, noff = (w >> 1) * 64;

    for (int k0 = 0; k0 < K; k0 += 32) {
        gload_lds16(Ag0 + k0, Al0);
        gload_lds16(Ag1 + k0, Al1);
        gload_lds16(Bg0 + k0, Bl0);
        gload_lds16(Bg1 + k0, Bl1);
        __syncthreads();
        bf16x8 af[4], bfr[4];
#pragma unroll
        for (int i = 0; i < 4; i++)
            af[i] = *(const bf16x8*)&As[(moff + i * 16 + mrow) * 32 + kq * 8];
#pragma unroll
        for (int j = 0; j < 4; j++)
            bfr[j] = *(const bf16x8*)&Bs[(noff + j * 16 + mrow) * 32 + kq * 8];
#pragma unroll
        for (int i = 0; i < 4; i++)
#pragma unroll
            for (int j = 0; j < 4; j++)
                acc[i][j] = __builtin_amdgcn_mfma_f32_16x16x32_bf16(
                    af[i], bfr[j], acc[i][j], 0, 0, 0);
        __syncthreads();
    }

    // epilogue: C/D layout col=lane&15, row=(lane>>4)*4+reg  [m89-verified]
    const int crow = (l >> 4) * 4, ccol = l & 15;
#pragma unroll
    for (int i = 0; i < 4; i++) {
#pragma unroll
        for (int j = 0; j < 4; j++) {
            long col = bn + noff + j * 16 + ccol;
            float bv = bias[col];
#pragma unroll
            for (int r = 0; r < 4; r++) {
                long row = bm + moff + i * 16 + crow + r;
                float v = acc[i][j][r] + bv;
                if (BF16OUT) ((ushort*)Cvoid)[row * (long)ldc + col] = f2bf(v);
                else         ((float*)Cvoid)[row * (long)ldc + col] = v;
            }
        }
    }
}

// ---------------------------------------------------------------------------
// Flash MQA attention, fp32 vector math, bf16 in/out.
// Block = (b, h, 32-query tile), 256 thr. Thread owns row ro=t>>3, cols a7+8j.
// Online softmax fully in-register: 8 lanes/row (same wave) shfl-reduce;
// P broadcast lane->lane via __shfl. 2 barriers per k-tile.
// ---------------------------------------------------------------------------
__global__ __launch_bounds__(256, 2) void attn_kernel(
    const ushort* __restrict__ qkvb, const float* __restrict__ pad,
    ushort* __restrict__ outp)
{
    const int qt = 63 - (int)blockIdx.x;   // big blocks first (causal tail)
    const int h  = blockIdx.y;
    const int b  = blockIdx.z;
    const int t  = threadIdx.x;
    const int ro = t >> 3, a7 = t & 7, lane = t & 63;

    __shared__ __align__(16) float Qs[32][132];
    __shared__ __align__(16) float Ks[32][132];
    __shared__ __align__(16) float Vs[32][132];
    __shared__ float padm[32];

    const long rowbase = (long)b * S_;

    // load Q tile [32 x 128] (bf16 -> fp32)
#pragma unroll
    for (int i = 0; i < 2; i++) {
        int idx = t + 256 * i;             // 0..511
        int r = idx >> 4, c8 = idx & 15;
        const ushort* src = qkvb + (rowbase + qt * 32 + r) * QKV_N + h * HD_ + c8 * 8;
        uint4 u = *(const uint4*)src;
        float* q = &Qs[r][c8 * 8];
        q[0] = __uint_as_float(u.x << 16); q[1] = __uint_as_float(u.x & 0xffff0000u);
        q[2] = __uint_as_float(u.y << 16); q[3] = __uint_as_float(u.y & 0xffff0000u);
        q[4] = __uint_as_float(u.z << 16); q[5] = __uint_as_float(u.z & 0xffff0000u);
        q[6] = __uint_as_float(u.w << 16); q[7] = __uint_as_float(u.w & 0xffff0000u);
    }

    float mrun = -1e30f, lrun = 0.f;
    float4 acc[4];
#pragma unroll
    for (int mi = 0; mi < 4; mi++) acc[mi] = make_float4(0.f, 0.f, 0.f, 0.f);

    const int qg = qt * 32 + ro;
    const float scale = 0.08838834764831845f;   // 1/sqrt(128)

    for (int kt = 0; kt <= qt; kt++) {
        // stage K,V tiles [32 x 128] (bf16 -> fp32)
#pragma unroll
        for (int i = 0; i < 2; i++) {
            int idx = t + 256 * i;
            int r = idx >> 4, c8 = idx & 15;
            const ushort* src = qkvb + (rowbase + kt * 32 + r) * QKV_N + c8 * 8;
            uint4 uk = *(const uint4*)(src + 2048);
            uint4 uv = *(const uint4*)(src + 2176);
            float* kd = &Ks[r][c8 * 8];
            float* vd = &Vs[r][c8 * 8];
            kd[0] = __uint_as_float(uk.x << 16); kd[1] = __uint_as_float(uk.x & 0xffff0000u);
            kd[2] = __uint_as_float(uk.y << 16); kd[3] = __uint_as_float(uk.y & 0xffff0000u);
            kd[4] = __uint_as_float(uk.z << 16); kd[5] = __uint_as_float(uk.z & 0xffff0000u);
            kd[6] = __uint_as_float(uk.w << 16); kd[7] = __uint_as_float(uk.w & 0xffff0000u);
            vd[0] = __uint_as_float(uv.x << 16); vd[1] = __uint_as_float(uv.x & 0xffff0000u);
            vd[2] = __uint_as_float(uv.y << 16); vd[3] = __uint_as_float(uv.y & 0xffff0000u);
            vd[4] = __uint_as_float(uv.z << 16); vd[5] = __uint_as_float(uv.z & 0xffff0000u);
            vd[6] = __uint_as_float(uv.w << 16); vd[7] = __uint_as_float(uv.w & 0xffff0000u);
        }
        if (t < 32) padm[t] = pad[rowbase + kt * 32 + t];
        __syncthreads();

        // ---- scores: row ro x cols {a7+8j} ----
        float s[4] = {0.f, 0.f, 0.f, 0.f};
#pragma unroll 8
        for (int d4 = 0; d4 < 32; d4++) {
            float4 q = *(const float4*)&Qs[ro][d4 * 4];
            float4 k0 = *(const float4*)&Ks[a7][d4 * 4];
            float4 k1 = *(const float4*)&Ks[a7 + 8][d4 * 4];
            float4 k2 = *(const float4*)&Ks[a7 + 16][d4 * 4];
            float4 k3 = *(const float4*)&Ks[a7 + 24][d4 * 4];
            s[0] += q.x * k0.x + q.y * k0.y + q.z * k0.z + q.w * k0.w;
            s[1] += q.x * k1.x + q.y * k1.y + q.z * k1.z + q.w * k1.w;
            s[2] += q.x * k2.x + q.y * k2.y + q.z * k2.z + q.w * k2.w;
            s[3] += q.x * k3.x + q.y * k3.y + q.z * k3.z + q.w * k3.w;
        }

        float mt = -1e30f;
#pragma unroll
        for (int j = 0; j < 4; j++) {
            int c = a7 + 8 * j;
            float v = s[j] * scale;
            if (kt * 32 + c > qg) v -= 1e9f;   // strict-causal
            v -= padm[c] * 1e9f;               // key padding
            s[j] = v;
            mt = fmaxf(mt, v);
        }
        // row reduction across the row's 8 lanes (same wave)
        mt = fmaxf(mt, __shfl_xor(mt, 1));
        mt = fmaxf(mt, __shfl_xor(mt, 2));
        mt = fmaxf(mt, __shfl_xor(mt, 4));
        float mn = fmaxf(mrun, mt);
        float alpha = __expf(mrun - mn);
        float p[4], sum = 0.f;
#pragma unroll
        for (int j = 0; j < 4; j++) { p[j] = __expf(s[j] - mn); sum += p[j]; }
        sum += __shfl_xor(sum, 1);
        sum += __shfl_xor(sum, 2);
        sum += __shfl_xor(sum, 4);
        lrun = lrun * alpha + sum;
        mrun = mn;
#pragma unroll
        for (int mi = 0; mi < 4; mi++) {
            acc[mi].x *= alpha; acc[mi].y *= alpha;
            acc[mi].z *= alpha; acc[mi].w *= alpha;
        }

        // ---- O += P @ V, P broadcast via shfl from owning lane ----
#pragma unroll
        for (int cc = 0; cc < 32; cc++) {
            float pc = __shfl(p[cc >> 3], (lane & 56) | (cc & 7));
#pragma unroll
            for (int mi = 0; mi < 4; mi++) {
                float4 v = *(const float4*)&Vs[cc][(a7 + 8 * mi) * 4];
                acc[mi].x = fmaf(pc, v.x, acc[mi].x);
                acc[mi].y = fmaf(pc, v.y, acc[mi].y);
                acc[mi].z = fmaf(pc, v.z, acc[mi].z);
                acc[mi].w = fmaf(pc, v.w, acc[mi].w);
            }
        }
        __syncthreads();
    }

    // epilogue: normalize, cast bf16, store [B*S][HID]
    float inv = 1.f / lrun;
    ushort* drow = outp + (rowbase + qt * 32 + ro) * (long)HID_ + h * HD_;
#pragma unroll
    for (int mi = 0; mi < 4; mi++) {
        ushort4 o;
        o.x = f2bf(acc[mi].x * inv);
        o.y = f2bf(acc[mi].y * inv);
        o.z = f2bf(acc[mi].z * inv);
        o.w = f2bf(acc[mi].w * inv);
        *(ushort4*)&drow[(a7 + 8 * mi) * 4] = o;
    }
}

// ---------------------------------------------------------------------------
extern "C" void kernel_launch(void* const* d_in, const int* in_sizes, int n_in,
                              void* d_out, int out_size, void* d_ws, size_t ws_size,
                              hipStream_t stream)
{
    const float* hidden = (const float*)d_in[0];
    // d_in[1] = causal mask: deterministic triu(k=1), hardcoded in attn_kernel
    const float* pad = (const float*)d_in[2];
    const float* Wq  = (const float*)d_in[3];
    const float* bq  = (const float*)d_in[4];
    const float* Wk  = (const float*)d_in[5];
    const float* bk  = (const float*)d_in[6];
    const float* Wv  = (const float*)d_in[7];
    const float* bv  = (const float*)d_in[8];
    const float* Wo  = (const float*)d_in[9];
    const float* bo  = (const float*)d_in[10];
    float* out = (float*)d_out;

    // workspace layout (bytes):
    char* ws = (char*)d_ws;
    ushort* hbf    = (ushort*)(ws);                    // [4096][2048] bf16  16.78 MB
    ushort* WqkvT  = (ushort*)(ws + 16777216);         // [2304][2048] bf16   9.44 MB
    ushort* WoT    = (ushort*)(ws + 26214400);         // [2048][2048] bf16   8.39 MB
    float*  bqkv   = (float*) (ws + 34603008);         // [2304] fp32        16 KB pad
    ushort* qkvb   = (ushort*)(ws + 34619392);         // [4096][2304] bf16  18.87 MB
    ushort* attnO  = (ushort*)(ws + 53493760);         // [4096][2048] bf16  16.78 MB
    // total 70,270,976 B

    cast_f32_bf16<<<4096, 256, 0, stream>>>(hidden, hbf);
    transcast<<<dim3(64, 64), 256, 0, stream>>>(Wq, WqkvT, 2048, 0);
    transcast<<<dim3(4, 64),  256, 0, stream>>>(Wk, WqkvT, 128, 2048);
    transcast<<<dim3(4, 64),  256, 0, stream>>>(Wv, WqkvT, 128, 2176);
    transcast<<<dim3(64, 64), 256, 0, stream>>>(Wo, WoT, 2048, 0);
    fuse_bias<<<9, 256, 0, stream>>>(bq, bk, bv, bqkv);

    gemm_mfma<true><<<dim3(18, 32), 256, 0, stream>>>(hbf, WqkvT, bqkv, qkvb,
                                                      HID_, QKV_N);
    attn_kernel<<<dim3(64, NH_, B_), 256, 0, stream>>>(qkvb, pad, attnO);
    gemm_mfma<false><<<dim3(16, 32), 256, 0, stream>>>(attnO, WoT, bo, out,
                                                       HID_, HID_);
}

// Round 3
// 351.272 us; speedup vs baseline: 8.9607x; 5.1581x over previous
//
#include <hip/hip_runtime.h>
#include <hip/hip_bf16.h>
#include <math.h>

// Problem constants (MultiQueryAttention_71734543778305)
#define B_    2
#define S_    2048
#define HID_  2048
#define NH_   16
#define HD_   128
#define MTOT  4096          // B*S
#define QKV_N 2304          // Q(2048) | K(128) | V(128)

typedef short bf16x8 __attribute__((ext_vector_type(8)));   // 8 bf16 in 4 VGPRs
typedef float f32x4  __attribute__((ext_vector_type(4)));
typedef float f32x16 __attribute__((ext_vector_type(16)));

__device__ __forceinline__ ushort f2bf(float f) {
    __hip_bfloat16 h = __float2bfloat16(f);   // RTNE
    ushort u; __builtin_memcpy(&u, &h, 2); return u;
}

// async global->LDS; LDS dest = wave-uniform base + lane*size
__device__ __forceinline__ void gload_lds16(const void* g, void* l) {
    __builtin_amdgcn_global_load_lds(
        (const __attribute__((address_space(1))) void*)g,
        (__attribute__((address_space(3))) void*)l, 16, 0, 0);
}
__device__ __forceinline__ void gload_lds4(const void* g, void* l) {
    __builtin_amdgcn_global_load_lds(
        (const __attribute__((address_space(1))) void*)g,
        (__attribute__((address_space(3))) void*)l, 4, 0, 0);
}

// ---------------------------------------------------------------------------
__global__ void cast_f32_bf16(const float* __restrict__ in, ushort* __restrict__ out)
{
    long i = ((long)blockIdx.x * 256 + threadIdx.x) * 8;
    float4 a = *(const float4*)&in[i];
    float4 b = *(const float4*)&in[i + 4];
    uint4 o;
    o.x = (uint)f2bf(a.x) | ((uint)f2bf(a.y) << 16);
    o.y = (uint)f2bf(a.z) | ((uint)f2bf(a.w) << 16);
    o.z = (uint)f2bf(b.x) | ((uint)f2bf(b.y) << 16);
    o.w = (uint)f2bf(b.z) | ((uint)f2bf(b.w) << 16);
    *(uint4*)&out[i] = o;
}

// W [2048][N] fp32 -> rows [rowoff..rowoff+N) of T[*][2048] bf16 (transposed)
__global__ void transcast(const float* __restrict__ W, ushort* __restrict__ T,
                          int N, int rowoff)
{
    __shared__ float tile[32][33];
    const int tx = threadIdx.x & 31, ty = threadIdx.x >> 5;
    const int n0 = blockIdx.x * 32, k0 = blockIdx.y * 32;
#pragma unroll
    for (int i = 0; i < 4; i++)
        tile[ty + 8 * i][tx] = W[(long)(k0 + ty + 8 * i) * N + n0 + tx];
    __syncthreads();
#pragma unroll
    for (int i = 0; i < 4; i++)
        T[(long)(rowoff + n0 + ty + 8 * i) * 2048 + k0 + tx] = f2bf(tile[tx][ty + 8 * i]);
}

__global__ void fuse_bias(const float* __restrict__ bq, const float* __restrict__ bk,
                          const float* __restrict__ bv, float* __restrict__ bqkv)
{
    int i = blockIdx.x * 256 + threadIdx.x;
    if (i < 2048)      bqkv[i] = bq[i];
    else if (i < 2176) bqkv[i] = bk[i - 2048];
    else if (i < QKV_N) bqkv[i] = bv[i - 2176];
}

// ---------------------------------------------------------------------------
// QKV GEMM (m97 structure), epilogue splits into qbuf / kbuf / vtbuf(V^T).
// ---------------------------------------------------------------------------
__global__ __launch_bounds__(256, 2) void gemm_qkv(
    const ushort* __restrict__ A, const ushort* __restrict__ Bt,
    const float* __restrict__ bias,
    ushort* __restrict__ qbuf, ushort* __restrict__ kbuf,
    ushort* __restrict__ vtbuf)
{
    const int K = HID_;
    __shared__ __align__(16) ushort As[128 * 32];
    __shared__ __align__(16) ushort Bs[128 * 32];
    const int t = threadIdx.x;
    const int w = t >> 6, l = t & 63;
    const long bm = (long)blockIdx.y * 128;
    const long bn = (long)blockIdx.x * 128;     // global col in [0, 2304)

    f32x4 acc[4][4];
#pragma unroll
    for (int i = 0; i < 4; i++)
#pragma unroll
        for (int j = 0; j < 4; j++) acc[i][j] = (f32x4){0.f, 0.f, 0.f, 0.f};

    const int srow = w * 16 + (l >> 2);
    const int scol = (l & 3) * 8;
    const ushort* Ag0 = A + (bm + srow) * (long)K + scol;
    const ushort* Ag1 = A + (bm + srow + 64) * (long)K + scol;
    const ushort* Bg0 = Bt + (bn + srow) * (long)K + scol;
    const ushort* Bg1 = Bt + (bn + srow + 64) * (long)K + scol;
    ushort* Al0 = As + w * 512;
    ushort* Al1 = As + 2048 + w * 512;
    ushort* Bl0 = Bs + w * 512;
    ushort* Bl1 = Bs + 2048 + w * 512;

    const int mrow = l & 15, kq = l >> 4;
    const int moff = (w & 1) * 64, noff = (w >> 1) * 64;

    for (int k0 = 0; k0 < K; k0 += 32) {
        gload_lds16(Ag0 + k0, Al0);
        gload_lds16(Ag1 + k0, Al1);
        gload_lds16(Bg0 + k0, Bl0);
        gload_lds16(Bg1 + k0, Bl1);
        __syncthreads();
        bf16x8 af[4], bfr[4];
#pragma unroll
        for (int i = 0; i < 4; i++)
            af[i] = *(const bf16x8*)&As[(moff + i * 16 + mrow) * 32 + kq * 8];
#pragma unroll
        for (int j = 0; j < 4; j++)
            bfr[j] = *(const bf16x8*)&Bs[(noff + j * 16 + mrow) * 32 + kq * 8];
#pragma unroll
        for (int i = 0; i < 4; i++)
#pragma unroll
            for (int j = 0; j < 4; j++)
                acc[i][j] = __builtin_amdgcn_mfma_f32_16x16x32_bf16(
                    af[i], bfr[j], acc[i][j], 0, 0, 0);
        __syncthreads();
    }

    const int crow = (l >> 4) * 4, ccol = l & 15;
    const int tile = blockIdx.x;
#pragma unroll
    for (int i = 0; i < 4; i++) {
#pragma unroll
        for (int j = 0; j < 4; j++) {
            long colg = bn + noff + j * 16 + ccol;
            float bv = bias[colg];
            long row0 = bm + moff + i * 16 + crow;
            float v[4];
#pragma unroll
            for (int r = 0; r < 4; r++) v[r] = acc[i][j][r] + bv;
            if (tile < 16) {
#pragma unroll
                for (int r = 0; r < 4; r++)
                    qbuf[(row0 + r) * (long)HID_ + colg] = f2bf(v[r]);
            } else if (tile == 16) {
                long ck = colg - 2048;
#pragma unroll
                for (int r = 0; r < 4; r++)
                    kbuf[(row0 + r) * (long)HD_ + ck] = f2bf(v[r]);
            } else {
                long cv = colg - 2176;
                long b  = row0 >> 11;          // tiles never cross batch
                long s0 = row0 & 2047;
                ushort4 pk;
                pk.x = f2bf(v[0]); pk.y = f2bf(v[1]);
                pk.z = f2bf(v[2]); pk.w = f2bf(v[3]);
                *(ushort4*)&vtbuf[b * (HD_ * (long)S_) + cv * (long)S_ + s0] = pk;
            }
        }
    }
}

// ---------------------------------------------------------------------------
// Generic bf16 MFMA GEMM, fp32 out (O-projection).
// ---------------------------------------------------------------------------
__global__ __launch_bounds__(256, 2) void gemm_mfma(
    const ushort* __restrict__ A, const ushort* __restrict__ Bt,
    const float* __restrict__ bias, float* __restrict__ C,
    int K, int ldc)
{
    __shared__ __align__(16) ushort As[128 * 32];
    __shared__ __align__(16) ushort Bs[128 * 32];
    const int t = threadIdx.x;
    const int w = t >> 6, l = t & 63;
    const long bm = (long)blockIdx.y * 128;
    const long bn = (long)blockIdx.x * 128;

    f32x4 acc[4][4];
#pragma unroll
    for (int i = 0; i < 4; i++)
#pragma unroll
        for (int j = 0; j < 4; j++) acc[i][j] = (f32x4){0.f, 0.f, 0.f, 0.f};

    const int srow = w * 16 + (l >> 2);
    const int scol = (l & 3) * 8;
    const ushort* Ag0 = A + (bm + srow) * (long)K + scol;
    const ushort* Ag1 = A + (bm + srow + 64) * (long)K + scol;
    const ushort* Bg0 = Bt + (bn + srow) * (long)K + scol;
    const ushort* Bg1 = Bt + (bn + srow + 64) * (long)K + scol;
    ushort* Al0 = As + w * 512;
    ushort* Al1 = As + 2048 + w * 512;
    ushort* Bl0 = Bs + w * 512;
    ushort* Bl1 = Bs + 2048 + w * 512;

    const int mrow = l & 15, kq = l >> 4;
    const int moff = (w & 1) * 64, noff = (w >> 1) * 64;

    for (int k0 = 0; k0 < K; k0 += 32) {
        gload_lds16(Ag0 + k0, Al0);
        gload_lds16(Ag1 + k0, Al1);
        gload_lds16(Bg0 + k0, Bl0);
        gload_lds16(Bg1 + k0, Bl1);
        __syncthreads();
        bf16x8 af[4], bfr[4];
#pragma unroll
        for (int i = 0; i < 4; i++)
            af[i] = *(const bf16x8*)&As[(moff + i * 16 + mrow) * 32 + kq * 8];
#pragma unroll
        for (int j = 0; j < 4; j++)
            bfr[j] = *(const bf16x8*)&Bs[(noff + j * 16 + mrow) * 32 + kq * 8];
#pragma unroll
        for (int i = 0; i < 4; i++)
#pragma unroll
            for (int j = 0; j < 4; j++)
                acc[i][j] = __builtin_amdgcn_mfma_f32_16x16x32_bf16(
                    af[i], bfr[j], acc[i][j], 0, 0, 0);
        __syncthreads();
    }

    const int crow = (l >> 4) * 4, ccol = l & 15;
#pragma unroll
    for (int i = 0; i < 4; i++) {
#pragma unroll
        for (int j = 0; j < 4; j++) {
            long col = bn + noff + j * 16 + ccol;
            float bv = bias[col];
#pragma unroll
            for (int r = 0; r < 4; r++) {
                long row = bm + moff + i * 16 + crow + r;
                C[row * (long)ldc + col] = acc[i][j][r] + bv;
            }
        }
    }
}

// ---------------------------------------------------------------------------
// MFMA flash MQA attention.
// Block = (b, h, 128-q tile); 4 waves x 32 q. K-tile = 64 keys.
// S^T = K·Q^T (32x32x16 MFMA, q in lane&31) -> scalar-per-lane online softmax
// -> P^T via shfl_xor(32) lane transform -> O^T += Vt·P^T.
// K LDS [64][128] and Vt LDS [128][64] are XOR-swizzled on 16B groups so both
// global_load_lds staging and b128 fragment reads are conflict-clean.
// ---------------------------------------------------------------------------
__global__ __launch_bounds__(256, 2) void attn_mfma(
    const ushort* __restrict__ qbuf, const ushort* __restrict__ kbuf,
    const ushort* __restrict__ vtbuf, const float* __restrict__ pad,
    ushort* __restrict__ outp)
{
    __shared__ __align__(16) char smem[34816];
    ushort* Ks   = (ushort*)smem;              // [64][128] bf16, swizzled
    ushort* Vt   = (ushort*)(smem + 16384);    // [128][64] bf16, swizzled
    float*  padL = (float*)(smem + 32768);     // [64]

    const int qblk = 15 - (int)blockIdx.x;     // big tiles first
    const int h = blockIdx.y, b = blockIdx.z;
    const int t = threadIdx.x, w = t >> 6, l = t & 63;
    const int l31 = l & 31, h5 = l >> 5;
    const long rowbase = (long)b * S_;
    const int qbase = qblk * 128 + w * 32;

    // Q B-fragments: B[k=feat][n=q], n=lane&31, k=(lane>>5)*8+j
    bf16x8 qf[8];
    {
        const ushort* qp = qbuf + (rowbase + qbase + l31) * (long)HID_
                                + h * HD_ + h5 * 8;
#pragma unroll
        for (int ks = 0; ks < 8; ks++) qf[ks] = *(const bf16x8*)(qp + ks * 16);
    }

    f32x16 o[4] = {};          // O^T [128 d][32 q]: 4 d-blocks of 32
    float mrun = -1e30f, lrun = 0.f;

    // staging pointers (kt-invariant lane offsets)
    const ushort* kg[4]; ushort* kl[4];
    const ushort* vg[4]; ushort* vl[4];
#pragma unroll
    for (int i = 0; i < 4; i++) {
        int key0 = w * 16 + i * 4 + (l >> 4);
        int gk = (l & 15) ^ (key0 & 15);
        kg[i] = kbuf + (rowbase + key0) * (long)HD_ + gk * 8;
        kl[i] = Ks + (w * 16 + i * 4) * 128 + l * 8;
        int d = w * 32 + i * 8 + (l >> 3);
        int gv = (l & 7) ^ (d & 7);
        vg[i] = vtbuf + ((long)b * HD_ + d) * (long)S_ + gv * 8;
        vl[i] = Vt + (w * 32 + i * 8) * 64 + l * 8;
    }

    const int kTiles = 2 * qblk + 2;
    const int qmaxw = qbase + 31;
    const float SC  = 0.08838834764831845f * 1.44269504089f;  // scale*log2e
    const float NEG = -1.0e9f * 1.44269504089f;

    for (int kt = 0; kt < kTiles; kt++) {
        const int ktb = kt * 64;
#pragma unroll
        for (int i = 0; i < 4; i++) gload_lds16(kg[i] + (long)ktb * HD_, kl[i]);
#pragma unroll
        for (int i = 0; i < 4; i++) gload_lds16(vg[i] + ktb, vl[i]);
        if (w == 0) gload_lds4(pad + rowbase + ktb + l, padL);
        __syncthreads();

        if (ktb <= qmaxw) {
            // ---- S^T = K · Q^T ----
            f32x16 c[2] = {};
#pragma unroll
            for (int mb = 0; mb < 2; mb++) {
                const int key = mb * 32 + l31;
#pragma unroll
                for (int ks = 0; ks < 8; ks++) {
                    int g = (ks * 2 + h5) ^ (key & 15);
                    bf16x8 a = *(const bf16x8*)&Ks[key * 128 + g * 8];
                    c[mb] = __builtin_amdgcn_mfma_f32_32x32x16_bf16(
                        a, qf[ks], c[mb], 0, 0, 0);
                }
            }
            // ---- masks + row max (row = r + 8g + 4h5 + 32mb, col q = l31) ----
            const bool causal = (ktb + 63) > qbase;
            const int qg = qbase + l31;
            float vmax = -3.0e38f;
#pragma unroll
            for (int mb = 0; mb < 2; mb++) {
#pragma unroll
                for (int g = 0; g < 4; g++) {
                    float4 pmv = *(const float4*)&padL[mb * 32 + 4 * h5 + 8 * g];
                    float pmr[4] = {pmv.x, pmv.y, pmv.z, pmv.w};
#pragma unroll
                    for (int r = 0; r < 4; r++) {
                        int reg = g * 4 + r;
                        float v = c[mb][reg] * SC + pmr[r] * NEG;
                        if (causal) {
                            int key = ktb + mb * 32 + 4 * h5 + 8 * g + r;
                            if (key > qg) v += NEG;
                        }
                        c[mb][reg] = v;
                        vmax = fmaxf(vmax, v);
                    }
                }
            }
            vmax = fmaxf(vmax, __shfl_xor(vmax, 32));
            float mnew  = fmaxf(mrun, vmax);
            float alpha = __builtin_amdgcn_exp2f(mrun - mnew);
            float sum = 0.f;
#pragma unroll
            for (int mb = 0; mb < 2; mb++)
#pragma unroll
                for (int reg = 0; reg < 16; reg++) {
                    float p = __builtin_amdgcn_exp2f(c[mb][reg] - mnew);
                    c[mb][reg] = p;
                    sum += p;
                }
            sum += __shfl_xor(sum, 32);
            lrun = lrun * alpha + sum;
            mrun = mnew;
#pragma unroll
            for (int mb = 0; mb < 4; mb++) o[mb] *= alpha;

            // ---- O^T += Vt · P^T ----
#pragma unroll
            for (int ks2 = 0; ks2 < 4; ks2++) {
                const int mbs = ks2 >> 1;
                const int base = (ks2 & 1) * 8;
                float own[4], oth[4];
#pragma unroll
                for (int i = 0; i < 4; i++) {
                    float ca = c[mbs][base + i];
                    float cb = c[mbs][base + 4 + i];
                    own[i] = h5 ? cb : ca;
                    oth[i] = h5 ? ca : cb;
                }
                float rec[4];
#pragma unroll
                for (int i = 0; i < 4; i++) rec[i] = __shfl_xor(oth[i], 32);
                bf16x8 pf;
#pragma unroll
                for (int i = 0; i < 4; i++) {
                    pf[i]     = (short)f2bf(h5 ? rec[i] : own[i]);
                    pf[4 + i] = (short)f2bf(h5 ? own[i] : rec[i]);
                }
#pragma unroll
                for (int mb = 0; mb < 4; mb++) {
                    int d = mb * 32 + l31;
                    int g = (ks2 * 2 + h5) ^ (d & 7);
                    bf16x8 a = *(const bf16x8*)&Vt[d * 64 + g * 8];
                    o[mb] = __builtin_amdgcn_mfma_f32_32x32x16_bf16(
                        a, pf, o[mb], 0, 0, 0);
                }
            }
        }
        __syncthreads();
    }

    // ---- epilogue: O^T -> O via LDS, coalesced bf16 stores ----
    ushort* Ob = (ushort*)smem + w * 4352;     // per-wave [32 q][136] bf16
    float inv = 1.f / lrun;
#pragma unroll
    for (int mb = 0; mb < 4; mb++) {
#pragma unroll
        for (int g = 0; g < 4; g++) {
            int d0 = mb * 32 + 4 * h5 + 8 * g;
            ushort4 pk;
            pk.x = f2bf(o[mb][g * 4 + 0] * inv);
            pk.y = f2bf(o[mb][g * 4 + 1] * inv);
            pk.z = f2bf(o[mb][g * 4 + 2] * inv);
            pk.w = f2bf(o[mb][g * 4 + 3] * inv);
            *(ushort4*)&Ob[l31 * 136 + d0] = pk;
        }
    }
    __builtin_amdgcn_s_waitcnt(0);   // wave-local LDS ordering
    {
        const int q = l >> 1, half = l & 1;
        const ushort* src = Ob + q * 136 + half * 64;
        ushort* dst = outp + (rowbase + qblk * 128 + w * 32 + q) * (long)HID_
                           + h * HD_ + half * 64;
#pragma unroll
        for (int i = 0; i < 8; i++) {
            uint4 v = *(const uint4*)(src + i * 8);
            *(uint4*)(dst + i * 8) = v;
        }
    }
}

// ---------------------------------------------------------------------------
extern "C" void kernel_launch(void* const* d_in, const int* in_sizes, int n_in,
                              void* d_out, int out_size, void* d_ws, size_t ws_size,
                              hipStream_t stream)
{
    const float* hidden = (const float*)d_in[0];
    // d_in[1] = causal mask: deterministic triu(k=1), hardcoded in attn_mfma
    const float* pad = (const float*)d_in[2];
    const float* Wq  = (const float*)d_in[3];
    const float* bq  = (const float*)d_in[4];
    const float* Wk  = (const float*)d_in[5];
    const float* bk  = (const float*)d_in[6];
    const float* Wv  = (const float*)d_in[7];
    const float* bv  = (const float*)d_in[8];
    const float* Wo  = (const float*)d_in[9];
    const float* bo  = (const float*)d_in[10];
    float* out = (float*)d_out;

    char* ws = (char*)d_ws;
    ushort* hbf   = (ushort*)(ws);                 // [4096][2048] bf16
    ushort* WqkvT = (ushort*)(ws + 16777216);      // [2304][2048] bf16
    ushort* WoT   = (ushort*)(ws + 26214400);      // [2048][2048] bf16
    float*  bqkv  = (float*) (ws + 34603008);      // [2304] f32
    ushort* qbuf  = (ushort*)(ws + 34619392);      // [2][2048][2048] bf16
    ushort* kbuf  = (ushort*)(ws + 51396608);      // [2][2048][128] bf16
    ushort* vtbuf = (ushort*)(ws + 52445184);      // [2][128][2048] bf16
    ushort* attnO = (ushort*)(ws + 53493760);      // [4096][2048] bf16
    // total 70,270,976 B

    cast_f32_bf16<<<4096, 256, 0, stream>>>(hidden, hbf);
    transcast<<<dim3(64, 64), 256, 0, stream>>>(Wq, WqkvT, 2048, 0);
    transcast<<<dim3(4, 64),  256, 0, stream>>>(Wk, WqkvT, 128, 2048);
    transcast<<<dim3(4, 64),  256, 0, stream>>>(Wv, WqkvT, 128, 2176);
    transcast<<<dim3(64, 64), 256, 0, stream>>>(Wo, WoT, 2048, 0);
    fuse_bias<<<9, 256, 0, stream>>>(bq, bk, bv, bqkv);

    gemm_qkv<<<dim3(18, 32), 256, 0, stream>>>(hbf, WqkvT, bqkv,
                                               qbuf, kbuf, vtbuf);
    attn_mfma<<<dim3(16, NH_, B_), 256, 0, stream>>>(qbuf, kbuf, vtbuf, pad,
                                                     attnO);
    gemm_mfma<<<dim3(16, 32), 256, 0, stream>>>(attnO, WoT, bo, out,
                                                HID_, HID_);
}